// Round 1
// baseline (273.059 us; speedup 1.0000x reference)
//
#include <hip/hip_runtime.h>
#include <math.h>

// Problem constants
#define B_TOT 2048
#define S_LEN 256
#define DIN   3
#define H     128
#define DOUT  6
#define DT_C  0.1f

#define HPAD 136   // bf16 row stride in LDS (128 + 8 pad): 272B rows, 16B aligned, breaks pow2 banks

typedef __attribute__((ext_vector_type(8))) short short8;
typedef __attribute__((ext_vector_type(4))) float f32x4;
typedef __attribute__((ext_vector_type(2))) unsigned int u32x2;

__device__ __forceinline__ unsigned short f2bf(float f) {
  unsigned int u = __float_as_uint(f);
  u += 0x7FFFu + ((u >> 16) & 1u);          // round-to-nearest-even
  return (unsigned short)(u >> 16);
}
__device__ __forceinline__ float bf2f(unsigned short h) {
  return __uint_as_float(((unsigned int)h) << 16);
}

// One block = 8 batch rows, 256 threads (4 waves). Wave w owns j in [w*32, w*32+32).
// Step GEMM via mfma_f32_16x16x32_bf16 with A = W_hh (m=j), B = h^T (n=b):
//   D[m][n] = sum_k W[j0+m][k] * h[b=n][k]  -> lane holds (b = lane&15, j = j0 + quad*4 + r)
// Split-bf16: W = Whi+Wlo (regs, loaded once), h = hhi+hlo (LDS round-trip each step).
__launch_bounds__(256)
__global__ void ltc_kernel(const float* __restrict__ x,
                           const float* __restrict__ W_xh,
                           const float* __restrict__ W_hh,
                           const float* __restrict__ b_hh,
                           const float* __restrict__ log_tau,
                           const float* __restrict__ fc_W,
                           const float* __restrict__ fc_b,
                           float* __restrict__ out) {
  __shared__ alignas(16) unsigned short sh_hi[16][HPAD];  // h_hi bf16, rows 8..15 stay zero
  __shared__ alignas(16) unsigned short sh_lo[16][HPAD];  // h_lo bf16
  __shared__ alignas(16) float sh_hf[8][132];             // final h fp32

  const int tid  = threadIdx.x;
  const int w    = tid >> 6;        // wave 0..3
  const int lane = tid & 63;
  const int quad = lane >> 4;       // 0..3
  const int l16  = lane & 15;       // b-column in B/D fragments
  const int rb0  = blockIdx.x * 8;  // first batch row of this block

  // ---- zero h LDS (rows 8..15 remain zero forever -> zero-padded B cols) ----
  for (int i = tid; i < 16 * HPAD; i += 256) {
    (&sh_hi[0][0])[i] = 0;
    (&sh_lo[0][0])[i] = 0;
  }

  // ---- W_hh A-fragments (hi/lo split), resident in registers for all 256 steps ----
  // A[m=l16][k = kc*32 + quad*8 + i],  j = w*32 + t*16 + m
  short8 wa_hi[2][4], wa_lo[2][4];
#pragma unroll
  for (int t = 0; t < 2; ++t) {
    const int j = w * 32 + t * 16 + l16;
#pragma unroll
    for (int kc = 0; kc < 4; ++kc) {
      const float* src = W_hh + j * H + kc * 32 + quad * 8;
#pragma unroll
      for (int i = 0; i < 8; ++i) {
        float wv = src[i];
        unsigned short hi = f2bf(wv);
        unsigned short lo = f2bf(wv - bf2f(hi));
        wa_hi[t][kc][i] = (short)hi;
        wa_lo[t][kc][i] = (short)lo;
      }
    }
  }

  // ---- per-lane epilogue constants for j = w*32 + t*16 + quad*4 + r ----
  float wx[2][4][3], bh[2][4], cc[2][4];
#pragma unroll
  for (int t = 0; t < 2; ++t)
#pragma unroll
    for (int r = 0; r < 4; ++r) {
      const int j = w * 32 + t * 16 + quad * 4 + r;
      wx[t][r][0] = W_xh[j * 3 + 0];
      wx[t][r][1] = W_xh[j * 3 + 1];
      wx[t][r][2] = W_xh[j * 3 + 2];
      bh[t][r]    = b_hh[j];
      float lt    = log_tau[j];
      float tau   = logf(1.f + expf(lt)) + 0.001f;  // softplus + eps (exact fp32, once)
      cc[t][r]    = DT_C / tau;
    }

  // ---- x stream for this lane's batch row (prefetch 1 step ahead) ----
  const int brow = l16 & 7;
  const bool valid = (l16 < 8);
  const float* xrow = x + (size_t)(rb0 + brow) * (S_LEN * DIN);
  float xc0 = xrow[0], xc1 = xrow[1], xc2 = xrow[2];

  float hreg[2][4] = {};  // fp32 h state, lane-resident (valid lanes only)

  __syncthreads();

  for (int s = 0; s < S_LEN; ++s) {
    // prefetch next step's x (independent of this step's compute)
    const int sn = (s < S_LEN - 1) ? s + 1 : s;
    float xn0 = xrow[sn * 3 + 0];
    float xn1 = xrow[sn * 3 + 1];
    float xn2 = xrow[sn * 3 + 2];

    // B-fragments of h^T from LDS: B[k = kc*32+quad*8+i][n = l16] = h[l16][k]
    short8 bf_hi[4], bf_lo[4];
#pragma unroll
    for (int kc = 0; kc < 4; ++kc) {
      const int off = kc * 32 + quad * 8;
      bf_hi[kc] = *(const short8*)&sh_hi[l16][off];
      bf_lo[kc] = *(const short8*)&sh_lo[l16][off];
    }

    f32x4 acc[2] = {{0.f, 0.f, 0.f, 0.f}, {0.f, 0.f, 0.f, 0.f}};
#pragma unroll
    for (int t = 0; t < 2; ++t) {
#pragma unroll
      for (int kc = 0; kc < 4; ++kc) {
        acc[t] = __builtin_amdgcn_mfma_f32_16x16x32_bf16(wa_lo[t][kc], bf_hi[kc], acc[t], 0, 0, 0);
        acc[t] = __builtin_amdgcn_mfma_f32_16x16x32_bf16(wa_hi[t][kc], bf_lo[kc], acc[t], 0, 0, 0);
        acc[t] = __builtin_amdgcn_mfma_f32_16x16x32_bf16(wa_hi[t][kc], bf_hi[kc], acc[t], 0, 0, 0);
      }
    }

    // epilogue: preact = Wh + b + x@W_xh^T ; f=tanh ; h += (DT/tau)*(f-h)   (all fp32)
#pragma unroll
    for (int t = 0; t < 2; ++t)
#pragma unroll
      for (int r = 0; r < 4; ++r) {
        float pre = acc[t][r] + bh[t][r]
                  + xc0 * wx[t][r][0] + xc1 * wx[t][r][1] + xc2 * wx[t][r][2];
        float e = __expf(2.f * pre);
        float f = 1.f - 2.f / (e + 1.f);     // tanh, safe at +/-inf
        hreg[t][r] += cc[t][r] * (f - hreg[t][r]);
      }

    __syncthreads();  // all waves done reading old h
    if (valid) {
#pragma unroll
      for (int t = 0; t < 2; ++t) {
        const int j0 = w * 32 + t * 16 + quad * 4;
        unsigned short h0 = f2bf(hreg[t][0]);
        unsigned short h1 = f2bf(hreg[t][1]);
        unsigned short h2 = f2bf(hreg[t][2]);
        unsigned short h3 = f2bf(hreg[t][3]);
        unsigned short l0 = f2bf(hreg[t][0] - bf2f(h0));
        unsigned short l1 = f2bf(hreg[t][1] - bf2f(h1));
        unsigned short l2 = f2bf(hreg[t][2] - bf2f(h2));
        unsigned short l3 = f2bf(hreg[t][3] - bf2f(h3));
        u32x2 vh, vl;
        vh.x = (unsigned)h0 | ((unsigned)h1 << 16);
        vh.y = (unsigned)h2 | ((unsigned)h3 << 16);
        vl.x = (unsigned)l0 | ((unsigned)l1 << 16);
        vl.y = (unsigned)l2 | ((unsigned)l3 << 16);
        *(u32x2*)&sh_hi[brow][j0] = vh;   // 8B store, 4-consecutive-j layout
        *(u32x2*)&sh_lo[brow][j0] = vl;
      }
    }
    __syncthreads();  // new h visible to all waves

    xc0 = xn0; xc1 = xn1; xc2 = xn2;
  }

  // ---- final head: params = softplus(h @ fc_W^T + fc_b), [8 x 6] per block ----
  if (valid) {
#pragma unroll
    for (int t = 0; t < 2; ++t) {
      const int j0 = w * 32 + t * 16 + quad * 4;
      f32x4 v = {hreg[t][0], hreg[t][1], hreg[t][2], hreg[t][3]};
      *(f32x4*)&sh_hf[brow][j0] = v;
    }
  }
  __syncthreads();

  if (tid < 8 * DOUT) {
    const int b = tid / DOUT;
    const int o = tid - b * DOUT;
    const float* fw = fc_W + o * H;
    float acc = fc_b[o];
#pragma unroll 4
    for (int k = 0; k < H; ++k) acc += sh_hf[b][k] * fw[k];
    float sp = (acc > 15.f) ? acc : logf(1.f + expf(acc));
    out[(rb0 + b) * DOUT + o] = sp;
  }
}

extern "C" void kernel_launch(void* const* d_in, const int* in_sizes, int n_in,
                              void* d_out, int out_size, void* d_ws, size_t ws_size,
                              hipStream_t stream) {
  const float* x       = (const float*)d_in[0];
  const float* W_xh    = (const float*)d_in[1];
  const float* W_hh    = (const float*)d_in[2];
  const float* b_hh    = (const float*)d_in[3];
  const float* log_tau = (const float*)d_in[4];
  const float* fc_W    = (const float*)d_in[5];
  const float* fc_b    = (const float*)d_in[6];
  float* out           = (float*)d_out;

  ltc_kernel<<<dim3(B_TOT / 8), dim3(256), 0, stream>>>(
      x, W_xh, W_hh, b_hh, log_tau, fc_W, fc_b, out);
}

// Round 2
// 220.562 us; speedup vs baseline: 1.2380x; 1.2380x over previous
//
#include <hip/hip_runtime.h>
#include <math.h>

// Problem constants
#define B_TOT 2048
#define S_LEN 256
#define DIN   3
#define H     128
#define DOUT  6
#define DT_C  0.1f

#define HPAD 136   // bf16 row stride in LDS (128 + 8 pad): 272B rows, 16B aligned

typedef __attribute__((ext_vector_type(8))) short short8;
typedef __attribute__((ext_vector_type(4))) float f32x4;
typedef __attribute__((ext_vector_type(2))) unsigned int u32x2;

__device__ __forceinline__ unsigned short f2bf(float f) {
  unsigned int u = __float_as_uint(f);
  u += 0x7FFFu + ((u >> 16) & 1u);          // round-to-nearest-even
  return (unsigned short)(u >> 16);
}
__device__ __forceinline__ float bf2f(unsigned short h) {
  return __uint_as_float(((unsigned int)h) << 16);
}

// One block = 8 batch rows, 512 threads (8 waves). Wave w owns j-tile [w*16, w*16+16).
// Step GEMM via mfma_f32_16x16x32_bf16, A = W_hh (m=j), B = h^T (n=b):
//   D[m][n] = sum_k W[j0+m][k] * h[b=n][k] -> lane holds (b = lane&15, j = w*16 + quad*4 + r)
// W split hi/lo in registers (fp32-grade accuracy); h stored bf16-only in LDS.
// Ping-pong h buffers -> ONE barrier per step.
__launch_bounds__(512, 2)
__global__ void ltc_kernel(const float* __restrict__ x,
                           const float* __restrict__ W_xh,
                           const float* __restrict__ W_hh,
                           const float* __restrict__ b_hh,
                           const float* __restrict__ log_tau,
                           const float* __restrict__ fc_W,
                           const float* __restrict__ fc_b,
                           float* __restrict__ out) {
  __shared__ alignas(16) unsigned short sh_h[2][16][HPAD];  // ping-pong h bf16; rows 8..15 stay 0
  __shared__ alignas(16) float sh_hf[8][132];               // final h fp32 for head

  const int tid  = threadIdx.x;
  const int w    = tid >> 6;        // wave 0..7 -> j-tile
  const int lane = tid & 63;
  const int quad = lane >> 4;       // 0..3
  const int l16  = lane & 15;       // b-column in B/D fragments
  const int rb0  = blockIdx.x * 8;  // first batch row of this block

  // ---- zero both h buffers (rows 8..15 remain zero -> zero-padded B cols) ----
  {
    uint4* p = (uint4*)&sh_h[0][0][0];
    const int n16 = (2 * 16 * HPAD) / 8;  // shorts -> uint4 count
    for (int i = tid; i < n16; i += 512) p[i] = make_uint4(0, 0, 0, 0);
  }

  // ---- W_hh A-fragments (hi/lo split), register-resident all 256 steps ----
  // A[m=l16][k = kc*32 + quad*8 + i],  j = w*16 + m
  short8 wa_hi[4], wa_lo[4];
  {
    const int j = w * 16 + l16;
#pragma unroll
    for (int kc = 0; kc < 4; ++kc) {
      const float* src = W_hh + j * H + kc * 32 + quad * 8;
#pragma unroll
      for (int i = 0; i < 8; ++i) {
        float wv = src[i];
        unsigned short hi = f2bf(wv);
        unsigned short lo = f2bf(wv - bf2f(hi));
        wa_hi[kc][i] = (short)hi;
        wa_lo[kc][i] = (short)lo;
      }
    }
  }

  // ---- per-lane epilogue constants for j = w*16 + quad*4 + r ----
  float wx[4][3], bh4[4], cc4[4];
#pragma unroll
  for (int r = 0; r < 4; ++r) {
    const int j = w * 16 + quad * 4 + r;
    wx[r][0] = W_xh[j * 3 + 0];
    wx[r][1] = W_xh[j * 3 + 1];
    wx[r][2] = W_xh[j * 3 + 2];
    bh4[r]   = b_hh[j];
    float lt = log_tau[j];
    float tau = logf(1.f + expf(lt)) + 0.001f;   // softplus + eps, exact fp32, once
    cc4[r]   = DT_C / tau;
  }

  // ---- x stream for this lane's batch row (prefetch 1 step ahead) ----
  const int brow = l16 & 7;
  const bool valid = (l16 < 8);
  const float* xrow = x + (size_t)(rb0 + brow) * (S_LEN * DIN);
  float xc0 = xrow[0], xc1 = xrow[1], xc2 = xrow[2];

  float hreg[4] = {0.f, 0.f, 0.f, 0.f};  // fp32 h state, lane-resident

  __syncthreads();

  for (int s = 0; s < S_LEN; ++s) {
    // prefetch next step's x (independent of this step's compute)
    const int sn = (s < S_LEN - 1) ? s + 1 : s;
    float xn0 = xrow[sn * 3 + 0];
    float xn1 = xrow[sn * 3 + 1];
    float xn2 = xrow[sn * 3 + 2];

    // B-fragments of h^T from current buffer: B[k = kc*32+quad*8+i][n = l16]
    const unsigned short (*hb)[HPAD] = sh_h[s & 1];
    short8 bf[4];
#pragma unroll
    for (int kc = 0; kc < 4; ++kc)
      bf[kc] = *(const short8*)&hb[l16][kc * 32 + quad * 8];

    // two independent 4-deep MFMA chains (Whi*h and Wlo*h)
    f32x4 ah = {0.f, 0.f, 0.f, 0.f};
    f32x4 al = {0.f, 0.f, 0.f, 0.f};
#pragma unroll
    for (int kc = 0; kc < 4; ++kc) {
      ah = __builtin_amdgcn_mfma_f32_16x16x32_bf16(wa_hi[kc], bf[kc], ah, 0, 0, 0);
      al = __builtin_amdgcn_mfma_f32_16x16x32_bf16(wa_lo[kc], bf[kc], al, 0, 0, 0);
    }

    // epilogue: preact = Wh + b + x@W_xh^T ; f=tanh ; h += (DT/tau)*(f-h)
#pragma unroll
    for (int r = 0; r < 4; ++r) {
      float pre = ah[r] + al[r] + bh4[r]
                + xc0 * wx[r][0] + xc1 * wx[r][1] + xc2 * wx[r][2];
      float e = __expf(2.f * pre);
      float f = 1.f - 2.f / (e + 1.f);     // tanh, safe at +/-inf
      hreg[r] += cc4[r] * (f - hreg[r]);
    }

    // write next-step h (bf16) into the OTHER buffer; one barrier separates steps
    if (valid) {
      unsigned short h0 = f2bf(hreg[0]);
      unsigned short h1 = f2bf(hreg[1]);
      unsigned short h2 = f2bf(hreg[2]);
      unsigned short h3 = f2bf(hreg[3]);
      u32x2 v;
      v.x = (unsigned)h0 | ((unsigned)h1 << 16);
      v.y = (unsigned)h2 | ((unsigned)h3 << 16);
      *(u32x2*)&sh_h[(s + 1) & 1][brow][w * 16 + quad * 4] = v;
    }
    __syncthreads();

    xc0 = xn0; xc1 = xn1; xc2 = xn2;
  }

  // ---- final head: params = softplus(h @ fc_W^T + fc_b), [8 x 6] per block ----
  if (valid) {
    f32x4 v = {hreg[0], hreg[1], hreg[2], hreg[3]};
    *(f32x4*)&sh_hf[brow][w * 16 + quad * 4] = v;
  }
  __syncthreads();

  if (tid < 8 * DOUT) {
    const int b = tid / DOUT;
    const int o = tid - b * DOUT;
    const float* fw = fc_W + o * H;
    float acc = fc_b[o];
#pragma unroll 4
    for (int k = 0; k < H; ++k) acc += sh_hf[b][k] * fw[k];
    float sp = (acc > 15.f) ? acc : logf(1.f + expf(acc));
    out[(rb0 + b) * DOUT + o] = sp;
  }
}

extern "C" void kernel_launch(void* const* d_in, const int* in_sizes, int n_in,
                              void* d_out, int out_size, void* d_ws, size_t ws_size,
                              hipStream_t stream) {
  const float* x       = (const float*)d_in[0];
  const float* W_xh    = (const float*)d_in[1];
  const float* W_hh    = (const float*)d_in[2];
  const float* b_hh    = (const float*)d_in[3];
  const float* log_tau = (const float*)d_in[4];
  const float* fc_W    = (const float*)d_in[5];
  const float* fc_b    = (const float*)d_in[6];
  float* out           = (float*)d_out;

  ltc_kernel<<<dim3(B_TOT / 8), dim3(512), 0, stream>>>(
      x, W_xh, W_hh, b_hh, log_tau, fc_W, fc_b, out);
}